// Round 5
// baseline (124.502 us; speedup 1.0000x reference)
//
#include <hip/hip_runtime.h>
#include <stdint.h>

// EATransformerMHS: B=2,H=12,S=256,E=64,L=25,K=768
// out[b,j,l,i] = sum_k p[b,k/64,i,j]*(v[b,k/64,j,k%64] + rel[b,i,j,k])*W[l,k] + b[l]
//
// Decomposition:  W_h.(v_h+rel_h)^T = W_h.rel_h^T  (bf16 MFMA, rel straight
// from per-lane float4 global loads)  +  wv[b,j,h,l]=W_h.v_h (f32 precompute,
// i-independent).  acc[l,i] += p[h,i] * (C_h[l,i] + wv[h,l]).
//
// Round-5: full 1-iteration-ahead software pipeline (rel, A-frags, wv, pt all
// prefetched into a second named buffer) -> no same-iteration load->use stalls.
// 4 waves/block (one 16-row i-tile each), no LDS, no barriers.

#define Bb 2
#define Hh 12
#define Ss 256
#define Ee 64
#define Ll 25
#define Kk 768

typedef __attribute__((ext_vector_type(8))) short bf16x8;
typedef __attribute__((ext_vector_type(4))) float f32x4;

#define NFRAG (Hh * 4)
#define AB_BYTES ((size_t)NFRAG * 64 * 8 * 2)   // 49152
#define PT_BYTES ((size_t)Bb * Ss * Hh * Ss * 4) // 6291456
#define WV_BYTES ((size_t)Bb * Ss * Hh * 32 * 4) // 786432

__device__ __forceinline__ ushort f2bf(float x) {  // RNE f32->bf16
    union { float f; uint32_t u; } u; u.f = x;
    uint32_t r = u.u + 0x7fff + ((u.u >> 16) & 1);
    return (ushort)(r >> 16);
}

// Pack W[L,K] into per-lane A-fragments: frag fi=h*4+ks*2+Lt,
// lane holds A[l=Lt*16+(lane&15), k=h*64+ks*32+(lane>>4)*8+t].
__global__ void a_pack_kernel(const float* __restrict__ W, ushort* __restrict__ ab) {
    int idx = blockIdx.x * 256 + threadIdx.x;
    if (idx >= NFRAG * 64) return;
    int lane = idx & 63, fi = idx >> 6;
    int Lt = fi & 1, ks = (fi >> 1) & 1, h = fi >> 2;
    int l = Lt * 16 + (lane & 15);
    int k0 = h * Ee + ks * 32 + (lane >> 4) * 8;
    ushort* dst = ab + (size_t)idx * 8;
#pragma unroll
    for (int t = 0; t < 8; ++t)
        dst[t] = (l < Ll) ? f2bf(W[l * Kk + k0 + t]) : (ushort)0;
}

// p[b][h][i][j] -> pt[b][j][h][i]
__global__ void p_transpose_kernel(const float* __restrict__ p,
                                   float* __restrict__ pt) {
    __shared__ float tile[32][33];
    const int bh = blockIdx.y;
    const int b = bh / Hh, h = bh % Hh;
    const int ti = blockIdx.x >> 3, tj = blockIdx.x & 7;
    const int tx = threadIdx.x & 31, ty = threadIdx.x >> 5;
#pragma unroll
    for (int s = 0; s < 4; ++s) {
        const int il = ty + 8 * s;
        tile[il][tx] = p[((size_t)(b * Hh + h) * Ss + ti * 32 + il) * Ss + tj * 32 + tx];
    }
    __syncthreads();
#pragma unroll
    for (int s = 0; s < 4; ++s) {
        const int jl = ty + 8 * s;
        pt[((size_t)(b * Ss + tj * 32 + jl) * Hh + h) * Ss + ti * 32 + tx] = tile[tx][jl];
    }
}

// wv[b][j][h][l(pad32)] = sum_e W[l, h*64+e] * v[b,h,j,e]   (f32 exact)
__global__ void wv_kernel(const float* __restrict__ W, const float* __restrict__ v,
                          float* __restrict__ wv) {
    const int bj = blockIdx.x;            // b*Ss + j
    const int b = bj >> 8, j = bj & (Ss - 1);
    const int t = threadIdx.x;            // 384 = 12h x 32l
    const int h = t >> 5, l = t & 31;
    float acc = 0.f;
    if (l < Ll) {
        const float* wrow = W + l * Kk + h * Ee;
        const float* vrow = v + ((size_t)(b * Hh + h) * Ss + j) * Ee;
#pragma unroll
        for (int e = 0; e < Ee; ++e) acc = __builtin_fmaf(wrow[e], vrow[e], acc);
    }
    wv[((size_t)bj * Hh + h) * 32 + l] = acc;
}

struct Ops {
    float4 c0, c1, c2, c3;        // rel (16 VGPR)
    bf16x8 A00, A01, A10, A11;    // A-frags (16)
    float4 w0, w1;                // wv rows (8)
    float pv;                     // p (1)
};

__global__ __launch_bounds__(256, 4) void mhs_pipe(
    const float* __restrict__ pt,   // [B,S,H,S]
    const float* __restrict__ rel,  // [B,S,S,K]
    const ushort* __restrict__ ab,  // packed A frags
    const float* __restrict__ wv,   // [B,S,H,32]
    const float* __restrict__ bias, // [L]
    float* __restrict__ out)        // [B,S,L,S]
{
    const int g = blockIdx.x;                 // [b][j][ig]
    const int ig = g & 3, j = (g >> 2) & (Ss - 1), b = g >> 10;
    const int tid = threadIdx.x;
    const int w = tid >> 6, lane = tid & 63;
    const int col = lane & 15, grp = lane >> 4;
    const int iw = ig * 64 + w * 16 + col;

    const float* relp = rel + ((size_t)(b * Ss + iw) * Ss + j) * Kk + grp * 8;
    const ushort* abl = ab + lane * 8;
    const float* wvb = wv + ((size_t)(b * Ss + j) * Hh) * 32 + grp * 4;
    const float* ptb = pt + ((size_t)(b * Ss + j) * Hh) * Ss + iw;

    f32x4 acc0 = {0.f, 0.f, 0.f, 0.f};
    f32x4 acc1 = {0.f, 0.f, 0.f, 0.f};

    auto load_ops = [&](Ops& o, int h) {
        const float* rb = relp + h * Ee;
        o.c0 = *(const float4*)(rb);
        o.c1 = *(const float4*)(rb + 4);
        o.c2 = *(const float4*)(rb + 32);
        o.c3 = *(const float4*)(rb + 36);
        const ushort* ap = abl + (size_t)h * 2048;
        o.A00 = *(const bf16x8*)(ap);
        o.A01 = *(const bf16x8*)(ap + 512);
        o.A10 = *(const bf16x8*)(ap + 1024);
        o.A11 = *(const bf16x8*)(ap + 1536);
        const float* wp = wvb + h * 32;
        o.w0 = *(const float4*)(wp);
        o.w1 = *(const float4*)(wp + 16);
        o.pv = ptb[h * Ss];
    };

    auto compute = [&](const Ops& o) {
        bf16x8 B0, B1;
#pragma unroll
        for (int t = 0; t < 4; ++t) {
            B0[t]     = (short)f2bf(((const float*)&o.c0)[t]);
            B0[t + 4] = (short)f2bf(((const float*)&o.c1)[t]);
            B1[t]     = (short)f2bf(((const float*)&o.c2)[t]);
            B1[t + 4] = (short)f2bf(((const float*)&o.c3)[t]);
        }
        f32x4 C0 = {0.f, 0.f, 0.f, 0.f}, C1 = {0.f, 0.f, 0.f, 0.f};
        C0 = __builtin_amdgcn_mfma_f32_16x16x32_bf16(o.A00, B0, C0, 0, 0, 0);
        C0 = __builtin_amdgcn_mfma_f32_16x16x32_bf16(o.A10, B1, C0, 0, 0, 0);
        C1 = __builtin_amdgcn_mfma_f32_16x16x32_bf16(o.A01, B0, C1, 0, 0, 0);
        C1 = __builtin_amdgcn_mfma_f32_16x16x32_bf16(o.A11, B1, C1, 0, 0, 0);
        const f32x4 wv0 = {o.w0.x, o.w0.y, o.w0.z, o.w0.w};
        const f32x4 wv1 = {o.w1.x, o.w1.y, o.w1.z, o.w1.w};
        acc0 += o.pv * (C0 + wv0);
        acc1 += o.pv * (C1 + wv1);
    };

    Ops oa, ob;
    load_ops(oa, 0);
#pragma unroll 1
    for (int h = 0; h < Hh; h += 2) {
        load_ops(ob, h + 1);
        compute(oa);
        load_ops(oa, (h + 2 < Hh) ? h + 2 : Hh - 1);  // last: dup (L1 hit), unused
        compute(ob);
    }

    // C/D layout: col=lane&15 (=i_local), row=(lane>>4)*4+r (=l in 16-tile)
#pragma unroll
    for (int r = 0; r < 4; ++r) {
        const int l0 = grp * 4 + r;
        out[((size_t)(b * Ss + j) * Ll + l0) * Ss + iw] = acc0[r] + bias[l0];
        const int l1 = 16 + grp * 4 + r;
        if (l1 < Ll)
            out[((size_t)(b * Ss + j) * Ll + l1) * Ss + iw] = acc1[r] + bias[l1];
    }
}

// Fallback (small ws): round-4 structure, no precomputed buffers.
__global__ __launch_bounds__(256, 4) void mhs_basic(
    const float* __restrict__ p, const float* __restrict__ v,
    const float* __restrict__ rel, const float* __restrict__ W,
    const float* __restrict__ bias, float* __restrict__ out)
{
    const int g = blockIdx.x;
    const int ig = g & 3, j = (g >> 2) & (Ss - 1), b = g >> 10;
    const int tid = threadIdx.x;
    const int w = tid >> 6, lane = tid & 63;
    const int col = lane & 15, grp = lane >> 4;
    const int iw = ig * 64 + w * 16 + col;
    const float* relp = rel + ((size_t)(b * Ss + iw) * Ss + j) * Kk + grp * 8;

    f32x4 acc0 = {0.f, 0.f, 0.f, 0.f}, acc1 = {0.f, 0.f, 0.f, 0.f};
#pragma unroll 1
    for (int h = 0; h < Hh; ++h) {
        bf16x8 A00, A01, A10, A11;
#pragma unroll
        for (int t = 0; t < 8; ++t) {
            const int kb = h * Ee + grp * 8 + t;
            const int la = col, lb = 16 + col;
            A00[t] = (short)f2bf(W[la * Kk + kb]);
            A01[t] = (lb < Ll) ? (short)f2bf(W[lb * Kk + kb]) : (short)0;
            A10[t] = (short)f2bf(W[la * Kk + kb + 32]);
            A11[t] = (lb < Ll) ? (short)f2bf(W[lb * Kk + kb + 32]) : (short)0;
        }
        const float* vbp = v + ((size_t)(b * Hh + h) * Ss + j) * Ee + grp * 8;
        const float4 va0 = *(const float4*)(vbp);
        const float4 va1 = *(const float4*)(vbp + 4);
        const float4 vc0 = *(const float4*)(vbp + 32);
        const float4 vc1 = *(const float4*)(vbp + 36);
        const float* rb = relp + h * Ee;
        const float4 c0 = *(const float4*)(rb);
        const float4 c1 = *(const float4*)(rb + 4);
        const float4 c2 = *(const float4*)(rb + 32);
        const float4 c3 = *(const float4*)(rb + 36);
        const float pv = p[((size_t)(b * Hh + h) * Ss + iw) * Ss + j];
        bf16x8 B0, B1;
#pragma unroll
        for (int t = 0; t < 4; ++t) {
            B0[t]     = (short)f2bf(((const float*)&c0)[t] + ((const float*)&va0)[t]);
            B0[t + 4] = (short)f2bf(((const float*)&c1)[t] + ((const float*)&va1)[t]);
            B1[t]     = (short)f2bf(((const float*)&c2)[t] + ((const float*)&vc0)[t]);
            B1[t + 4] = (short)f2bf(((const float*)&c3)[t] + ((const float*)&vc1)[t]);
        }
        f32x4 C0 = {0.f, 0.f, 0.f, 0.f}, C1 = {0.f, 0.f, 0.f, 0.f};
        C0 = __builtin_amdgcn_mfma_f32_16x16x32_bf16(A00, B0, C0, 0, 0, 0);
        C0 = __builtin_amdgcn_mfma_f32_16x16x32_bf16(A10, B1, C0, 0, 0, 0);
        C1 = __builtin_amdgcn_mfma_f32_16x16x32_bf16(A01, B0, C1, 0, 0, 0);
        C1 = __builtin_amdgcn_mfma_f32_16x16x32_bf16(A11, B1, C1, 0, 0, 0);
        acc0 += pv * C0;
        acc1 += pv * C1;
    }
#pragma unroll
    for (int r = 0; r < 4; ++r) {
        const int l0 = grp * 4 + r;
        out[((size_t)(b * Ss + j) * Ll + l0) * Ss + iw] = acc0[r] + bias[l0];
        const int l1 = 16 + grp * 4 + r;
        if (l1 < Ll)
            out[((size_t)(b * Ss + j) * Ll + l1) * Ss + iw] = acc1[r] + bias[l1];
    }
}

extern "C" void kernel_launch(void* const* d_in, const int* in_sizes, int n_in,
                              void* d_out, int out_size, void* d_ws, size_t ws_size,
                              hipStream_t stream) {
    const float* p    = (const float*)d_in[0];
    const float* v    = (const float*)d_in[1];
    const float* rel  = (const float*)d_in[2];
    const float* W    = (const float*)d_in[3];
    const float* bias = (const float*)d_in[4];
    float* out = (float*)d_out;

    const int nblk = Bb * Ss * 4;  // 2048 blocks x 256 threads
    const bool full = ws_size >= AB_BYTES + PT_BYTES + WV_BYTES;

    if (full) {
        ushort* ab = (ushort*)d_ws;
        float* pt = (float*)((char*)d_ws + AB_BYTES);
        float* wvp = (float*)((char*)d_ws + AB_BYTES + PT_BYTES);
        hipLaunchKernelGGL(a_pack_kernel, dim3((NFRAG * 64 + 255) / 256), dim3(256),
                           0, stream, W, ab);
        hipLaunchKernelGGL(p_transpose_kernel, dim3(64, Bb * Hh), dim3(256),
                           0, stream, p, pt);
        hipLaunchKernelGGL(wv_kernel, dim3(Bb * Ss), dim3(Hh * 32),
                           0, stream, W, v, wvp);
        hipLaunchKernelGGL(mhs_pipe, dim3(nblk), dim3(256), 0, stream,
                           pt, rel, ab, wvp, bias, out);
    } else {
        hipLaunchKernelGGL(mhs_basic, dim3(nblk), dim3(256), 0, stream,
                           p, v, rel, W, bias, out);
    }
}

// Round 6
// 123.563 us; speedup vs baseline: 1.0076x; 1.0076x over previous
//
#include <hip/hip_runtime.h>
#include <stdint.h>

// EATransformerMHS: B=2,H=12,S=256,E=64,L=25,K=768
// out[b,j,l,i] = sum_k p[b,k/64,i,j]*(v[b,k/64,j,k%64] + rel[b,i,j,k])*W[l,k] + b[l]
//
// Decomposition:
//   MFMA term: acc[l,i] = sum_h mfma(W_h, bf16(p[h,i]*rel_h[i,:]))   (p folded into B)
//   value term (i-indep GEMM collapsed): acc[l,i] += sum_h p[h,i]*wv[b,j,h,l], wv=W_h.v_h
// h-loop is a 2-buffer software pipeline carrying ONLY {rel 16, A 16, pv 1} VGPRs
// per buffer; loads for h+1 issue BEFORE compute of h, so the consume-wait is
// vmcnt(9) and prefetch stays in flight (vmcnt is in-issue-order!).
// No LDS, no barriers. 4 waves/block, one 16-row i-tile per wave.

#define Bb 2
#define Hh 12
#define Ss 256
#define Ee 64
#define Ll 25
#define Kk 768

typedef __attribute__((ext_vector_type(8))) short bf16x8;
typedef __attribute__((ext_vector_type(4))) float f32x4;

#define NFRAG (Hh * 4)
#define AB_BYTES ((size_t)NFRAG * 64 * 8 * 2)    // 49152
#define PT_BYTES ((size_t)Bb * Ss * Hh * Ss * 4) // 6291456
#define WV_BYTES ((size_t)Bb * Ss * Hh * 32 * 4) // 786432

__device__ __forceinline__ ushort f2bf(float x) {  // RNE f32->bf16
    union { float f; uint32_t u; } u; u.f = x;
    uint32_t r = u.u + 0x7fff + ((u.u >> 16) & 1);
    return (ushort)(r >> 16);
}

// Pack W[L,K] into per-lane A-fragments: frag fi=h*4+ks*2+Lt,
// lane holds A[l=Lt*16+(lane&15), k=h*64+ks*32+(lane>>4)*8+t].
__global__ void a_pack_kernel(const float* __restrict__ W, ushort* __restrict__ ab) {
    int idx = blockIdx.x * 256 + threadIdx.x;
    if (idx >= NFRAG * 64) return;
    int lane = idx & 63, fi = idx >> 6;
    int Lt = fi & 1, ks = (fi >> 1) & 1, h = fi >> 2;
    int l = Lt * 16 + (lane & 15);
    int k0 = h * Ee + ks * 32 + (lane >> 4) * 8;
    ushort* dst = ab + (size_t)idx * 8;
#pragma unroll
    for (int t = 0; t < 8; ++t)
        dst[t] = (l < Ll) ? f2bf(W[l * Kk + k0 + t]) : (ushort)0;
}

// p[b][h][i][j] -> pt[b][j][h][i]
__global__ void p_transpose_kernel(const float* __restrict__ p,
                                   float* __restrict__ pt) {
    __shared__ float tile[32][33];
    const int bh = blockIdx.y;
    const int b = bh / Hh, h = bh % Hh;
    const int ti = blockIdx.x >> 3, tj = blockIdx.x & 7;
    const int tx = threadIdx.x & 31, ty = threadIdx.x >> 5;
#pragma unroll
    for (int s = 0; s < 4; ++s) {
        const int il = ty + 8 * s;
        tile[il][tx] = p[((size_t)(b * Hh + h) * Ss + ti * 32 + il) * Ss + tj * 32 + tx];
    }
    __syncthreads();
#pragma unroll
    for (int s = 0; s < 4; ++s) {
        const int jl = ty + 8 * s;
        pt[((size_t)(b * Ss + tj * 32 + jl) * Hh + h) * Ss + ti * 32 + tx] = tile[tx][jl];
    }
}

// wv[b][j][h][l(pad32)] = sum_e W[l, h*64+e] * v[b,h,j,e]   (f32 exact)
__global__ void wv_kernel(const float* __restrict__ W, const float* __restrict__ v,
                          float* __restrict__ wv) {
    const int bj = blockIdx.x;
    const int b = bj >> 8, j = bj & (Ss - 1);
    const int t = threadIdx.x;            // 384 = 12h x 32l
    const int h = t >> 5, l = t & 31;
    float acc = 0.f;
    if (l < Ll) {
        const float* wrow = W + l * Kk + h * Ee;
        const float* vrow = v + ((size_t)(b * Hh + h) * Ss + j) * Ee;
#pragma unroll
        for (int e = 0; e < Ee; ++e) acc = __builtin_fmaf(wrow[e], vrow[e], acc);
    }
    wv[((size_t)bj * Hh + h) * 32 + l] = acc;
}

struct Buf {
    float4 r0, r1, r2, r3;        // rel (16 VGPR)
    bf16x8 A00, A01, A10, A11;    // A-frags (16 VGPR)
    float pv;                     // p (1 VGPR)
};

__global__ __launch_bounds__(256, 4) void mhs_pipe2(
    const float* __restrict__ pt,   // [B,S,H,S]
    const float* __restrict__ rel,  // [B,S,S,K]
    const ushort* __restrict__ ab,  // packed A frags
    const float* __restrict__ wv,   // [B,S,H,32]
    const float* __restrict__ bias, // [L]
    float* __restrict__ out)        // [B,S,L,S]
{
    // XCD-bijective swizzle: 2048 blocks, 8 XCDs, 256 per XCD; blocks sharing
    // (b,j) land on the same XCD (pt/wv/out L2 locality).
    const int m = (blockIdx.x & 7) * 256 + (blockIdx.x >> 3);
    const int ig = m & 3, j = (m >> 2) & (Ss - 1), b = m >> 10;
    const int tid = threadIdx.x;
    const int w = tid >> 6, lane = tid & 63;
    const int col = lane & 15, grp = lane >> 4;
    const int iw = ig * 64 + w * 16 + col;

    const float* relp = rel + ((size_t)(b * Ss + iw) * Ss + j) * Kk + grp * 8;
    const ushort* abl = ab + lane * 8;
    const float* ptb = pt + ((size_t)(b * Ss + j) * Hh) * Ss + iw;
    const float* wvb = wv + ((size_t)(b * Ss + j) * Hh) * 32 + grp * 4;

    f32x4 acc0 = {0.f, 0.f, 0.f, 0.f};
    f32x4 acc1 = {0.f, 0.f, 0.f, 0.f};

    auto load = [&](Buf& o, int h) {
        const float* rb = relp + h * Ee;
        o.r0 = *(const float4*)(rb);
        o.r1 = *(const float4*)(rb + 4);
        o.r2 = *(const float4*)(rb + 32);
        o.r3 = *(const float4*)(rb + 36);
        const ushort* ap = abl + (size_t)h * 2048;
        o.A00 = *(const bf16x8*)(ap);
        o.A01 = *(const bf16x8*)(ap + 512);
        o.A10 = *(const bf16x8*)(ap + 1024);
        o.A11 = *(const bf16x8*)(ap + 1536);
        o.pv = ptb[h * Ss];
    };

    auto compute = [&](const Buf& o) {
        const float s = o.pv;
        bf16x8 B0, B1;
#pragma unroll
        for (int t = 0; t < 4; ++t) {
            B0[t]     = (short)f2bf(s * ((const float*)&o.r0)[t]);
            B0[t + 4] = (short)f2bf(s * ((const float*)&o.r1)[t]);
            B1[t]     = (short)f2bf(s * ((const float*)&o.r2)[t]);
            B1[t + 4] = (short)f2bf(s * ((const float*)&o.r3)[t]);
        }
        acc0 = __builtin_amdgcn_mfma_f32_16x16x32_bf16(o.A00, B0, acc0, 0, 0, 0);
        acc0 = __builtin_amdgcn_mfma_f32_16x16x32_bf16(o.A10, B1, acc0, 0, 0, 0);
        acc1 = __builtin_amdgcn_mfma_f32_16x16x32_bf16(o.A01, B0, acc1, 0, 0, 0);
        acc1 = __builtin_amdgcn_mfma_f32_16x16x32_bf16(o.A11, B1, acc1, 0, 0, 0);
    };

    Buf oa, ob;
    load(oa, 0);
#pragma unroll 1
    for (int h = 0; h < Hh; h += 2) {
        load(ob, h + 1);          // issued BEFORE compute(oa): stays in flight
        compute(oa);              // waits only the older buffer (vmcnt(9))
        if (h + 2 < Hh) load(oa, h + 2);   // uniform branch; no dup on last
        compute(ob);
    }

    // value term: acc[l,i] += sum_h pv[h] * wv[h,l]   (f32 exact, once/wave)
    f32x4 val0 = {0.f, 0.f, 0.f, 0.f};
    f32x4 val1 = {0.f, 0.f, 0.f, 0.f};
#pragma unroll
    for (int h = 0; h < Hh; ++h) {
        const float pvh = ptb[h * Ss];
        const f32x4 w0 = *(const f32x4*)(wvb + h * 32);
        const f32x4 w1 = *(const f32x4*)(wvb + h * 32 + 16);
        val0 += pvh * w0;
        val1 += pvh * w1;
    }
    acc0 += val0;
    acc1 += val1;

    // C/D layout: col=lane&15 (=i_local), row=(lane>>4)*4+r (=l in 16-tile)
#pragma unroll
    for (int r = 0; r < 4; ++r) {
        const int l0 = grp * 4 + r;
        out[((size_t)(b * Ss + j) * Ll + l0) * Ss + iw] = acc0[r] + bias[l0];
        const int l1 = 16 + grp * 4 + r;
        if (l1 < Ll)
            out[((size_t)(b * Ss + j) * Ll + l1) * Ss + iw] = acc1[r] + bias[l1];
    }
}

// Fallback (small ws): self-contained, no precomputed buffers.
__global__ __launch_bounds__(256, 4) void mhs_basic(
    const float* __restrict__ p, const float* __restrict__ v,
    const float* __restrict__ rel, const float* __restrict__ W,
    const float* __restrict__ bias, float* __restrict__ out)
{
    const int g = blockIdx.x;
    const int ig = g & 3, j = (g >> 2) & (Ss - 1), b = g >> 10;
    const int tid = threadIdx.x;
    const int w = tid >> 6, lane = tid & 63;
    const int col = lane & 15, grp = lane >> 4;
    const int iw = ig * 64 + w * 16 + col;
    const float* relp = rel + ((size_t)(b * Ss + iw) * Ss + j) * Kk + grp * 8;

    f32x4 acc0 = {0.f, 0.f, 0.f, 0.f}, acc1 = {0.f, 0.f, 0.f, 0.f};
#pragma unroll 1
    for (int h = 0; h < Hh; ++h) {
        bf16x8 A00, A01, A10, A11;
#pragma unroll
        for (int t = 0; t < 8; ++t) {
            const int kb = h * Ee + grp * 8 + t;
            const int la = col, lb = 16 + col;
            A00[t] = (short)f2bf(W[la * Kk + kb]);
            A01[t] = (lb < Ll) ? (short)f2bf(W[lb * Kk + kb]) : (short)0;
            A10[t] = (short)f2bf(W[la * Kk + kb + 32]);
            A11[t] = (lb < Ll) ? (short)f2bf(W[lb * Kk + kb + 32]) : (short)0;
        }
        const float* vbp = v + ((size_t)(b * Hh + h) * Ss + j) * Ee + grp * 8;
        const float4 va0 = *(const float4*)(vbp);
        const float4 va1 = *(const float4*)(vbp + 4);
        const float4 vc0 = *(const float4*)(vbp + 32);
        const float4 vc1 = *(const float4*)(vbp + 36);
        const float* rb = relp + h * Ee;
        const float4 c0 = *(const float4*)(rb);
        const float4 c1 = *(const float4*)(rb + 4);
        const float4 c2 = *(const float4*)(rb + 32);
        const float4 c3 = *(const float4*)(rb + 36);
        const float pv = p[((size_t)(b * Hh + h) * Ss + iw) * Ss + j];
        bf16x8 B0, B1;
#pragma unroll
        for (int t = 0; t < 4; ++t) {
            B0[t]     = (short)f2bf(((const float*)&c0)[t] + ((const float*)&va0)[t]);
            B0[t + 4] = (short)f2bf(((const float*)&c1)[t] + ((const float*)&va1)[t]);
            B1[t]     = (short)f2bf(((const float*)&c2)[t] + ((const float*)&vc0)[t]);
            B1[t + 4] = (short)f2bf(((const float*)&c3)[t] + ((const float*)&vc1)[t]);
        }
        f32x4 C0 = {0.f, 0.f, 0.f, 0.f}, C1 = {0.f, 0.f, 0.f, 0.f};
        C0 = __builtin_amdgcn_mfma_f32_16x16x32_bf16(A00, B0, C0, 0, 0, 0);
        C0 = __builtin_amdgcn_mfma_f32_16x16x32_bf16(A10, B1, C0, 0, 0, 0);
        C1 = __builtin_amdgcn_mfma_f32_16x16x32_bf16(A01, B0, C1, 0, 0, 0);
        C1 = __builtin_amdgcn_mfma_f32_16x16x32_bf16(A11, B1, C1, 0, 0, 0);
        acc0 += pv * C0;
        acc1 += pv * C1;
    }
#pragma unroll
    for (int r = 0; r < 4; ++r) {
        const int l0 = grp * 4 + r;
        out[((size_t)(b * Ss + j) * Ll + l0) * Ss + iw] = acc0[r] + bias[l0];
        const int l1 = 16 + grp * 4 + r;
        if (l1 < Ll)
            out[((size_t)(b * Ss + j) * Ll + l1) * Ss + iw] = acc1[r] + bias[l1];
    }
}

extern "C" void kernel_launch(void* const* d_in, const int* in_sizes, int n_in,
                              void* d_out, int out_size, void* d_ws, size_t ws_size,
                              hipStream_t stream) {
    const float* p    = (const float*)d_in[0];
    const float* v    = (const float*)d_in[1];
    const float* rel  = (const float*)d_in[2];
    const float* W    = (const float*)d_in[3];
    const float* bias = (const float*)d_in[4];
    float* out = (float*)d_out;

    const int nblk = Bb * Ss * 4;  // 2048 blocks x 256 threads
    const bool full = ws_size >= AB_BYTES + PT_BYTES + WV_BYTES;

    if (full) {
        ushort* ab = (ushort*)d_ws;
        float* pt = (float*)((char*)d_ws + AB_BYTES);
        float* wvp = (float*)((char*)d_ws + AB_BYTES + PT_BYTES);
        hipLaunchKernelGGL(a_pack_kernel, dim3((NFRAG * 64 + 255) / 256), dim3(256),
                           0, stream, W, ab);
        hipLaunchKernelGGL(p_transpose_kernel, dim3(64, Bb * Hh), dim3(256),
                           0, stream, p, pt);
        hipLaunchKernelGGL(wv_kernel, dim3(Bb * Ss), dim3(Hh * 32),
                           0, stream, W, v, wvp);
        hipLaunchKernelGGL(mhs_pipe2, dim3(nblk), dim3(256), 0, stream,
                           pt, rel, ab, wvp, bias, out);
    } else {
        hipLaunchKernelGGL(mhs_basic, dim3(nblk), dim3(256), 0, stream,
                           p, v, rel, W, bias, out);
    }
}